// Round 5
// baseline (303.048 us; speedup 1.0000x reference)
//
#include <hip/hip_runtime.h>
#include <hip/hip_bf16.h>
#include <stdint.h>

#define NN 50000
#define NE 800000
#define NB 196            // dst buckets: dst>>8 (256 nodes each)
#define EPB 2048
#define NBLK ((NE + EPB - 1) / EPB)   // 391

typedef __attribute__((ext_vector_type(8))) __bf16 bf16x8;
typedef __attribute__((ext_vector_type(4))) float f32x4;
typedef __attribute__((ext_vector_type(4))) int i32x4;

__device__ __forceinline__ float bflo(uint32_t u) { return __uint_as_float(u << 16); }
__device__ __forceinline__ float bfhi(uint32_t u) { return __uint_as_float(u & 0xffff0000u); }
__device__ __forceinline__ uint16_t f2bf(float f) {
    uint32_t u = __float_as_uint(f);
    u += 0x7fffu + ((u >> 16) & 1u);   // RNE
    return (uint16_t)(u >> 16);
}
__device__ __forceinline__ float bf2f(uint16_t h) { return __uint_as_float(((uint32_t)h) << 16); }

// bijective XCD-chunked block swizzle (m204 variant)
__device__ __forceinline__ int xcd_swz(int bid, int nwg) {
    int q = nwg >> 3, r = nwg & 7;
    int xcd = bid & 7, idx = bid >> 3;
    int base = (xcd < r) ? xcd * (q + 1) : r * (q + 1) + (xcd - r) * q;
    return base + idx;
}

// per-block edge-layout detection (int64 vs int32)
__device__ __forceinline__ int detect_i64(const int* ei, int* sh_cnt) {
    int t = threadIdx.x;
    if (t == 0) *sh_cnt = 0;
    __syncthreads();
    if (t < 64) atomicAdd(sh_cnt, (ei[2 * t + 1] != 0) ? 1 : 0);
    __syncthreads();
    return (*sh_cnt < 4) ? 1 : 0;
}

// per-block x-dtype detection (fp32 vs bf16)
__device__ __forceinline__ int detect_fp32(const uint32_t* xu, int* sh_cnt) {
    int t = threadIdx.x;
    if (t == 0) *sh_cnt = 0;
    __syncthreads();
    uint32_t u = xu[t & 255];
    uint32_t lo = u & 0xffffu;
    uint32_t e = (lo >> 7) & 0xffu;
    int ok = (lo == 0u) || (e >= 96u && e <= 150u);
    if (t < 256) atomicAdd(sh_cnt, ok);
    __syncthreads();
    return (*sh_cnt < 192) ? 1 : 0;
}

// ---------------- pass 1: per-block bucket histograms ----------------
__global__ __launch_bounds__(256) void hist_pass(const int* __restrict__ ei,
                                                 int* __restrict__ histM) {
    __shared__ int hist[NB];
    __shared__ int shc;
    int fl = detect_i64(ei, &shc);
    for (int i = threadIdx.x; i < NB; i += 256) hist[i] = 0;
    __syncthreads();
    int base = blockIdx.x * EPB;
    for (int i = 0; i < EPB; i += 256) {
        int e = base + i + threadIdx.x;
        if (e < NE) {
            int d = fl ? ei[2 * NE + 2 * e] : ei[NE + e];
            atomicAdd(&hist[d >> 8], 1);
        }
    }
    __syncthreads();
    for (int i = threadIdx.x; i < NB; i += 256) histM[i * NBLK + blockIdx.x] = hist[i];
}

// ---------------- pass 2: per-bucket scan over block counts ----------------
__global__ __launch_bounds__(512) void scan_rows(int* __restrict__ histM, int* __restrict__ bucket_tot) {
    __shared__ int sm[512];
    int b = blockIdx.x, t = threadIdx.x;
    int v = (t < NBLK) ? histM[b * NBLK + t] : 0;
    sm[t] = v;
    __syncthreads();
    for (int o = 1; o < 512; o <<= 1) {
        int x = (t >= o) ? sm[t - o] : 0;
        __syncthreads();
        sm[t] += x;
        __syncthreads();
    }
    if (t < NBLK) histM[b * NBLK + t] = sm[t] - v;   // exclusive prefix in-place
    if (t == 511) bucket_tot[b] = sm[511];
}

// ---------------- pass 3: scatter edges into reserved bucket runs ----------------
__global__ __launch_bounds__(256) void scatter_pass(const int* __restrict__ ei,
                                                    const int* __restrict__ histM,
                                                    const int* __restrict__ bucket_tot,
                                                    uint32_t* __restrict__ staging) {
    __shared__ int sm[256];
    __shared__ int curs[NB];
    __shared__ int shc;
    int fl = detect_i64(ei, &shc);
    int blk = blockIdx.x, t = threadIdx.x;
    int v = (t < NB) ? bucket_tot[t] : 0;
    sm[t] = v;
    __syncthreads();
    for (int o = 1; o < 256; o <<= 1) {
        int x = (t >= o) ? sm[t - o] : 0;
        __syncthreads();
        sm[t] += x;
        __syncthreads();
    }
    if (t < NB) curs[t] = (sm[t] - v) + histM[t * NBLK + blk];
    __syncthreads();
    int base = blk * EPB;
    for (int i = 0; i < EPB; i += 256) {
        int e = base + i + t;
        if (e < NE) {
            int s, d;
            if (fl) { s = ei[2 * e]; d = ei[2 * NE + 2 * e]; }
            else    { s = ei[e];     d = ei[NE + e]; }
            int p = atomicAdd(&curs[d >> 8], 1);
            staging[p] = ((uint32_t)(d & 0xff) << 16) | (uint32_t)s;
        }
    }
}

// ---------------- pass 4: per-bucket CSR build ----------------
__global__ __launch_bounds__(256) void build_csr(const uint32_t* __restrict__ staging,
                                                 const int* __restrict__ bucket_tot,
                                                 int* __restrict__ row_start, int* __restrict__ deg,
                                                 float* __restrict__ inv_deg, int* __restrict__ csr) {
    __shared__ int degs[256];
    __shared__ int sm[256];
    __shared__ int curs[256];
    __shared__ int beg_s, cnt_s;
    int b = blockIdx.x, t = threadIdx.x;
    int v = (t < NB) ? bucket_tot[t] : 0;
    sm[t] = v;
    __syncthreads();
    for (int o = 1; o < 256; o <<= 1) {
        int x = (t >= o) ? sm[t - o] : 0;
        __syncthreads();
        sm[t] += x;
        __syncthreads();
    }
    if (t == b) { beg_s = sm[t] - v; cnt_s = v; }
    __syncthreads();
    int beg = beg_s, cnt = cnt_s;
    degs[t] = 0;
    __syncthreads();
    for (int i = t; i < cnt; i += 256) atomicAdd(&degs[(staging[beg + i] >> 16) & 0xff], 1);
    __syncthreads();
    int d = degs[t];
    sm[t] = d;
    __syncthreads();
    for (int o = 1; o < 256; o <<= 1) {
        int x = (t >= o) ? sm[t - o] : 0;
        __syncthreads();
        sm[t] += x;
        __syncthreads();
    }
    int excl = sm[t] - d;
    curs[t] = excl;
    int node = b * 256 + t;
    if (node < NN) {
        row_start[node] = beg + excl;
        deg[node] = d;
        inv_deg[node] = 1.0f / (float)(d > 0 ? d : 1);
    }
    __syncthreads();
    for (int i = t; i < cnt; i += 256) {
        uint32_t u = staging[beg + i];
        int dl = (u >> 16) & 0xff;
        int p = atomicAdd(&curs[dl], 1);
        csr[beg + p] = (int)(u & 0xffffu);
    }
}

// ---------------- merged: norm_x (blocks 0..6249) + weight swizzle ----------------
#define NORMX_BLKS 6250   // NN*32/256
__global__ __launch_bounds__(256) void norm_all(const void* __restrict__ x,
                                                const void* __restrict__ w1l, const void* __restrict__ b1,
                                                const void* __restrict__ w1r, const void* __restrict__ w2l,
                                                const void* __restrict__ b2, const void* __restrict__ w2r,
                                                uint32_t* __restrict__ xb,
                                                uint16_t* __restrict__ w1l_sw, uint16_t* __restrict__ w1r_sw,
                                                uint16_t* __restrict__ w2l_sw, uint16_t* __restrict__ w2r_sw,
                                                uint16_t* __restrict__ bias_buf) {
    __shared__ int shc;
    int fp32 = detect_fp32((const uint32_t*)x, &shc);
    if (blockIdx.x < NORMX_BLKS) {
        int i = blockIdx.x * 256 + threadIdx.x;  // < NN*32
        if (fp32) {
            f32x4 v = ((const f32x4*)x)[i];
            uint2 o;
            o.x = (uint32_t)f2bf(v[0]) | ((uint32_t)f2bf(v[1]) << 16);
            o.y = (uint32_t)f2bf(v[2]) | ((uint32_t)f2bf(v[3]) << 16);
            ((uint2*)xb)[i] = o;
        } else {
            ((uint2*)xb)[i] = ((const uint2*)x)[i];
        }
        return;
    }
    int tid = (blockIdx.x - NORMX_BLKS) * 256 + threadIdx.x;
    if (tid < 16384) {
        int frag = tid >> 6, lane = tid & 63;
        const void* srcw; uint16_t* dst; int N; int fl;
        if (frag < 64)       { srcw = w1l; dst = w1l_sw; N = 256; fl = frag; }
        else if (frag < 128) { srcw = w1r; dst = w1r_sw; N = 256; fl = frag - 64; }
        else if (frag < 192) { srcw = w2l; dst = w2l_sw; N = 128; fl = frag - 128; }
        else                 { srcw = w2r; dst = w2r_sw; N = 128; fl = frag - 192; }
        int NTm = N >> 4;
        int kt = fl / NTm, nt = fl - kt * NTm;
        int k0 = kt * 32 + (lane >> 4) * 8, n = nt * 16 + (lane & 15);
        uint16_t* d = dst + (size_t)fl * 512 + lane * 8;
#pragma unroll
        for (int j = 0; j < 8; j++) {
            int si = (k0 + j) * N + n;
            d[j] = fp32 ? f2bf(((const float*)srcw)[si]) : ((const uint16_t*)srcw)[si];
        }
    } else if (tid < 16384 + 384) {
        int j = tid - 16384;
        const void* s = (j < 256) ? b1 : b2;
        int jj = (j < 256) ? j : j - 256;
        bias_buf[j] = fp32 ? f2bf(((const float*)s)[jj]) : ((const uint16_t*)s)[jj];
    }
}

// ---------------- fused layer 1: gather-mean (LDS tile) + dual GEMM + relu ----------------
// Block = 64 dst nodes. Phase A: each half-wave gathers 2 nodes concurrently (8-deep)
// into padded LDS tile [64][136] bf16. Phase B: h_blk = agg@W1 + x@W2 (A1 from LDS,
// A2 self-rows from global). Phase C: bias+relu, 2-round LDS staging, coalesced stores.
#define ATW 136   // bf16 per row: 128 + 8 pad (272 B stride, 16B-aligned)
__global__ __launch_bounds__(256) void fused_l1(const uint32_t* __restrict__ xu,
                                                const int* __restrict__ row_start,
                                                const int* __restrict__ deg,
                                                const int* __restrict__ csr,
                                                const float* __restrict__ inv_deg,
                                                const uint16_t* __restrict__ xb16,
                                                const uint16_t* __restrict__ W1sw,
                                                const uint16_t* __restrict__ W2sw,
                                                const uint16_t* __restrict__ bias,
                                                uint16_t* __restrict__ H) {
    __shared__ __align__(16) uint16_t atile[64][ATW];   // 17.4 KB agg tile
    __shared__ __align__(16) uint16_t stg[64][136];     // 17.4 KB epilogue staging
    int node0 = blockIdx.x * 64;
    int tid = threadIdx.x;
    int wave = tid >> 6, lane = tid & 63;
    int half = lane >> 5, l = lane & 31;

    // ---- phase A: gather-mean; half-wave owns 2 concurrent nodes, 8-deep each ----
    for (int pp = 0; pp < 4; pp++) {
        int nlA = wave * 16 + pp * 4 + half * 2;
        int nlB = nlA + 1;
        int na = node0 + nlA; na = (na < NN) ? na : (NN - 1);
        int nb = node0 + nlB; nb = (nb < NN) ? nb : (NN - 1);
        int begA = row_start[na], endA = begA + deg[na];
        int begB = row_start[nb], endB = begB + deg[nb];
        float alx[8], ahx[8], aly[8], ahy[8];
        float blx[8], bhx[8], bly[8], bhy[8];
#pragma unroll
        for (int k = 0; k < 8; k++) {
            alx[k] = 0.f; ahx[k] = 0.f; aly[k] = 0.f; ahy[k] = 0.f;
            blx[k] = 0.f; bhx[k] = 0.f; bly[k] = 0.f; bhy[k] = 0.f;
        }
        int ja = begA, jb = begB;
        for (; ja + 8 <= endA && jb + 8 <= endB; ja += 8, jb += 8) {
            int ia[8], ib[8];
#pragma unroll
            for (int k = 0; k < 8; k++) { ia[k] = csr[ja + k]; ib[k] = csr[jb + k]; }
#pragma unroll
            for (int k = 0; k < 8; k++) {
                uint2 va = *(const uint2*)(xu + (size_t)ia[k] * 64 + l * 2);
                uint2 vb = *(const uint2*)(xu + (size_t)ib[k] * 64 + l * 2);
                alx[k] += bflo(va.x); ahx[k] += bfhi(va.x);
                aly[k] += bflo(va.y); ahy[k] += bfhi(va.y);
                blx[k] += bflo(vb.x); bhx[k] += bfhi(vb.x);
                bly[k] += bflo(vb.y); bhy[k] += bfhi(vb.y);
            }
        }
        for (; ja + 8 <= endA; ja += 8) {
            int ia[8];
#pragma unroll
            for (int k = 0; k < 8; k++) ia[k] = csr[ja + k];
#pragma unroll
            for (int k = 0; k < 8; k++) {
                uint2 va = *(const uint2*)(xu + (size_t)ia[k] * 64 + l * 2);
                alx[k] += bflo(va.x); ahx[k] += bfhi(va.x);
                aly[k] += bflo(va.y); ahy[k] += bfhi(va.y);
            }
        }
        for (; jb + 8 <= endB; jb += 8) {
            int ib[8];
#pragma unroll
            for (int k = 0; k < 8; k++) ib[k] = csr[jb + k];
#pragma unroll
            for (int k = 0; k < 8; k++) {
                uint2 vb = *(const uint2*)(xu + (size_t)ib[k] * 64 + l * 2);
                blx[k] += bflo(vb.x); bhx[k] += bfhi(vb.x);
                bly[k] += bflo(vb.y); bhy[k] += bfhi(vb.y);
            }
        }
        for (; ja < endA; ja++) {
            uint2 va = *(const uint2*)(xu + (size_t)csr[ja] * 64 + l * 2);
            alx[0] += bflo(va.x); ahx[0] += bfhi(va.x);
            aly[0] += bflo(va.y); ahy[0] += bfhi(va.y);
        }
        for (; jb < endB; jb++) {
            uint2 vb = *(const uint2*)(xu + (size_t)csr[jb] * 64 + l * 2);
            blx[0] += bflo(vb.x); bhx[0] += bfhi(vb.x);
            bly[0] += bflo(vb.y); bhy[0] += bfhi(vb.y);
        }
        float sa = inv_deg[na], sb = inv_deg[nb];
        float a0 = (((alx[0] + alx[1]) + (alx[2] + alx[3])) + ((alx[4] + alx[5]) + (alx[6] + alx[7]))) * sa;
        float a1 = (((ahx[0] + ahx[1]) + (ahx[2] + ahx[3])) + ((ahx[4] + ahx[5]) + (ahx[6] + ahx[7]))) * sa;
        float a2 = (((aly[0] + aly[1]) + (aly[2] + aly[3])) + ((aly[4] + aly[5]) + (aly[6] + aly[7]))) * sa;
        float a3 = (((ahy[0] + ahy[1]) + (ahy[2] + ahy[3])) + ((ahy[4] + ahy[5]) + (ahy[6] + ahy[7]))) * sa;
        float b0 = (((blx[0] + blx[1]) + (blx[2] + blx[3])) + ((blx[4] + blx[5]) + (blx[6] + blx[7]))) * sb;
        float b1v = (((bhx[0] + bhx[1]) + (bhx[2] + bhx[3])) + ((bhx[4] + bhx[5]) + (bhx[6] + bhx[7]))) * sb;
        float b2v = (((bly[0] + bly[1]) + (bly[2] + bly[3])) + ((bly[4] + bly[5]) + (bly[6] + bly[7]))) * sb;
        float b3 = (((bhy[0] + bhy[1]) + (bhy[2] + bhy[3])) + ((bhy[4] + bhy[5]) + (bhy[6] + bhy[7]))) * sb;
        uint2 oa, ob;
        oa.x = (uint32_t)f2bf(a0) | ((uint32_t)f2bf(a1) << 16);
        oa.y = (uint32_t)f2bf(a2) | ((uint32_t)f2bf(a3) << 16);
        ob.x = (uint32_t)f2bf(b0) | ((uint32_t)f2bf(b1v) << 16);
        ob.y = (uint32_t)f2bf(b2v) | ((uint32_t)f2bf(b3) << 16);
        *(uint2*)((char*)&atile[nlA][0] + l * 8) = oa;
        *(uint2*)((char*)&atile[nlB][0] + l * 8) = ob;
    }
    __syncthreads();

    // ---- phase B: dual GEMM, out [64][256]; wave (wr,wc) tile = 32 rows x 128 cols ----
    int wr = wave >> 1, wc = wave & 1;
    int m = lane & 15, q = lane >> 4;
    int ar[2];
#pragma unroll
    for (int rf = 0; rf < 2; rf++) {
        int r = node0 + wr * 32 + rf * 16 + m;
        ar[rf] = (r < NN) ? r : (NN - 1);
    }
    f32x4 acc[2][8];
#pragma unroll
    for (int rf = 0; rf < 2; rf++)
#pragma unroll
        for (int nt = 0; nt < 8; nt++)
#pragma unroll
            for (int i = 0; i < 4; i++) acc[rf][nt][i] = 0.f;

#pragma unroll
    for (int kt = 0; kt < 4; kt++) {
        bf16x8 a1f[2], a2f[2];
#pragma unroll
        for (int rf = 0; rf < 2; rf++) {
            a1f[rf] = *(const bf16x8*)((const char*)atile +
                        (size_t)(wr * 32 + rf * 16 + m) * (ATW * 2) + kt * 64 + q * 16);
            a2f[rf] = *(const bf16x8*)(xb16 + (size_t)ar[rf] * 128 + kt * 32 + q * 8);
        }
#pragma unroll
        for (int nt = 0; nt < 8; nt++) {
            int gnt = wc * 8 + nt;
            bf16x8 B1 = *(const bf16x8*)(W1sw + ((size_t)(kt * 16 + gnt)) * 512 + lane * 8);
            bf16x8 B2 = *(const bf16x8*)(W2sw + ((size_t)(kt * 16 + gnt)) * 512 + lane * 8);
            acc[0][nt] = __builtin_amdgcn_mfma_f32_16x16x32_bf16(a1f[0], B1, acc[0][nt], 0, 0, 0);
            acc[1][nt] = __builtin_amdgcn_mfma_f32_16x16x32_bf16(a1f[1], B1, acc[1][nt], 0, 0, 0);
            acc[0][nt] = __builtin_amdgcn_mfma_f32_16x16x32_bf16(a2f[0], B2, acc[0][nt], 0, 0, 0);
            acc[1][nt] = __builtin_amdgcn_mfma_f32_16x16x32_bf16(a2f[1], B2, acc[1][nt], 0, 0, 0);
        }
    }

    // ---- phase C: bias + relu -> 2-round LDS staging -> coalesced stores ----
#pragma unroll
    for (int r = 0; r < 2; r++) {
        if (wc == r) {
#pragma unroll
            for (int nt = 0; nt < 8; nt++) {
                int cl = nt * 16 + m;
                float bv = bf2f(bias[r * 128 + cl]);
#pragma unroll
                for (int rf = 0; rf < 2; rf++)
#pragma unroll
                    for (int i = 0; i < 4; i++) {
                        float v = fmaxf(acc[rf][nt][i] + bv, 0.f);
                        stg[wr * 32 + rf * 16 + q * 4 + i][cl] = f2bf(v);
                    }
            }
        }
        __syncthreads();
#pragma unroll
        for (int rr = 0; rr < 4; rr++) {
            int row = rr * 16 + (tid >> 4);
            int grow = node0 + row;
            if (grow < NN)
                *(i32x4*)(H + (size_t)grow * 256 + r * 128 + (tid & 15) * 8) =
                    *(const i32x4*)&stg[row][(tid & 15) * 8];
        }
        __syncthreads();
    }
}

// ---------------- layer-2 GEMM v3: t = A@W1 (bf16), u = A@W2 + bias (fp32) ----------------
__global__ __launch_bounds__(256) void gemm2_v3(const uint16_t* __restrict__ A,
                                                const uint16_t* __restrict__ W1sw,
                                                const uint16_t* __restrict__ W2sw,
                                                const uint16_t* __restrict__ bias,
                                                uint16_t* __restrict__ T,
                                                float* __restrict__ U) {
    __shared__ __align__(16) uint16_t ts[64][72];   // 9216 B
    __shared__ __align__(16) float us[64][68];      // 17408 B
    int wg = xcd_swz(blockIdx.x, 1564);
    int rg = wg >> 1, cg = wg & 1;
    int wave = threadIdx.x >> 6, lane = threadIdx.x & 63;
    int wr = wave >> 1, wc = wave & 1;
    int m = lane & 15, q = lane >> 4;
    int rowbase = rg * 64 + wr * 32;
    int gnt0 = cg * 4 + wc * 2;      // global 16-col frag base, NTF=8

    int ar[2];
#pragma unroll
    for (int rf = 0; rf < 2; rf++) {
        int r = rowbase + rf * 16 + m;
        ar[rf] = (r < NN) ? r : (NN - 1);
    }

    f32x4 acc1[2][2], acc2[2][2];
#pragma unroll
    for (int rf = 0; rf < 2; rf++)
#pragma unroll
        for (int nt = 0; nt < 2; nt++)
#pragma unroll
            for (int i = 0; i < 4; i++) { acc1[rf][nt][i] = 0.f; acc2[rf][nt][i] = 0.f; }

#pragma unroll
    for (int kt = 0; kt < 8; kt++) {
        bf16x8 b10 = *(const bf16x8*)(W1sw + ((size_t)(kt * 8 + gnt0 + 0)) * 512 + lane * 8);
        bf16x8 b11 = *(const bf16x8*)(W1sw + ((size_t)(kt * 8 + gnt0 + 1)) * 512 + lane * 8);
        bf16x8 b20 = *(const bf16x8*)(W2sw + ((size_t)(kt * 8 + gnt0 + 0)) * 512 + lane * 8);
        bf16x8 b21 = *(const bf16x8*)(W2sw + ((size_t)(kt * 8 + gnt0 + 1)) * 512 + lane * 8);
        bf16x8 a0 = *(const bf16x8*)(A + (size_t)ar[0] * 256 + kt * 32 + q * 8);
        bf16x8 a1 = *(const bf16x8*)(A + (size_t)ar[1] * 256 + kt * 32 + q * 8);
        acc1[0][0] = __builtin_amdgcn_mfma_f32_16x16x32_bf16(a0, b10, acc1[0][0], 0, 0, 0);
        acc1[0][1] = __builtin_amdgcn_mfma_f32_16x16x32_bf16(a0, b11, acc1[0][1], 0, 0, 0);
        acc1[1][0] = __builtin_amdgcn_mfma_f32_16x16x32_bf16(a1, b10, acc1[1][0], 0, 0, 0);
        acc1[1][1] = __builtin_amdgcn_mfma_f32_16x16x32_bf16(a1, b11, acc1[1][1], 0, 0, 0);
        acc2[0][0] = __builtin_amdgcn_mfma_f32_16x16x32_bf16(a0, b20, acc2[0][0], 0, 0, 0);
        acc2[0][1] = __builtin_amdgcn_mfma_f32_16x16x32_bf16(a0, b21, acc2[0][1], 0, 0, 0);
        acc2[1][0] = __builtin_amdgcn_mfma_f32_16x16x32_bf16(a1, b20, acc2[1][0], 0, 0, 0);
        acc2[1][1] = __builtin_amdgcn_mfma_f32_16x16x32_bf16(a1, b21, acc2[1][1], 0, 0, 0);
    }

#pragma unroll
    for (int rf = 0; rf < 2; rf++)
#pragma unroll
        for (int nt = 0; nt < 2; nt++) {
            int coll = wc * 32 + nt * 16 + m;
            float bv = bf2f(bias[cg * 64 + coll]);
#pragma unroll
            for (int i = 0; i < 4; i++) {
                int rl = wr * 32 + rf * 16 + q * 4 + i;
                ts[rl][coll] = f2bf(acc1[rf][nt][i]);
                us[rl][coll] = acc2[rf][nt][i] + bv;
            }
        }
    __syncthreads();
    int tt = threadIdx.x;
#pragma unroll
    for (int rr = 0; rr < 2; rr++) {
        int row = rr * 32 + (tt >> 3);
        int grow = rg * 64 + row;
        if (grow < NN)
            *(i32x4*)(T + (size_t)grow * 128 + cg * 64 + (tt & 7) * 8) =
                *(const i32x4*)&ts[row][(tt & 7) * 8];
    }
#pragma unroll
    for (int rr = 0; rr < 4; rr++) {
        int row = rr * 16 + (tt >> 4);
        int grow = rg * 64 + row;
        if (grow < NN)
            *(f32x4*)(U + (size_t)grow * 128 + cg * 64 + (tt & 15) * 4) =
                *(const f32x4*)&us[row][(tt & 15) * 4];
    }
}

// final: out = mean_gather(t) + u, fp32 out; 2 nodes/wave, dwordx2 gathers, float4 stores
__global__ __launch_bounds__(256) void agg_final_v2(const uint32_t* __restrict__ tu,
                                                    const int* __restrict__ row_start,
                                                    const int* __restrict__ deg,
                                                    const int* __restrict__ csr,
                                                    const float* __restrict__ inv_deg,
                                                    const f32x4* __restrict__ u,
                                                    f32x4* __restrict__ out) {
    int wave = threadIdx.x >> 6, lane = threadIdx.x & 63;
    int half = lane >> 5, l = lane & 31;
    int node = blockIdx.x * 8 + wave * 2 + half;
    int beg = row_start[node], end = beg + deg[node];
    float lx[8], hx[8], ly[8], hy[8];
#pragma unroll
    for (int k = 0; k < 8; k++) { lx[k] = 0.f; hx[k] = 0.f; ly[k] = 0.f; hy[k] = 0.f; }
    int j = beg;
    for (; j + 8 <= end; j += 8) {
        int idx[8];
#pragma unroll
        for (int k = 0; k < 8; k++) idx[k] = csr[j + k];
#pragma unroll
        for (int k = 0; k < 8; k++) {
            uint2 v = *(const uint2*)(tu + (size_t)idx[k] * 64 + l * 2);
            lx[k] += bflo(v.x); hx[k] += bfhi(v.x);
            ly[k] += bflo(v.y); hy[k] += bfhi(v.y);
        }
    }
    for (; j < end; j++) {
        uint2 v = *(const uint2*)(tu + (size_t)csr[j] * 64 + l * 2);
        lx[0] += bflo(v.x); hx[0] += bfhi(v.x);
        ly[0] += bflo(v.y); hy[0] += bfhi(v.y);
    }
    float sc = inv_deg[node];
    f32x4 uv = u[(size_t)node * 32 + l];
    f32x4 r;
    r[0] = (((lx[0] + lx[1]) + (lx[2] + lx[3])) + ((lx[4] + lx[5]) + (lx[6] + lx[7]))) * sc + uv[0];
    r[1] = (((hx[0] + hx[1]) + (hx[2] + hx[3])) + ((hx[4] + hx[5]) + (hx[6] + hx[7]))) * sc + uv[1];
    r[2] = (((ly[0] + ly[1]) + (ly[2] + ly[3])) + ((ly[4] + ly[5]) + (ly[6] + ly[7]))) * sc + uv[2];
    r[3] = (((hy[0] + hy[1]) + (hy[2] + hy[3])) + ((hy[4] + hy[5]) + (hy[6] + hy[7]))) * sc + uv[3];
    out[(size_t)node * 32 + l] = r;
}

extern "C" void kernel_launch(void* const* d_in, const int* in_sizes, int n_in,
                              void* d_out, int out_size, void* d_ws, size_t ws_size,
                              hipStream_t stream) {
    const void* x_raw  = d_in[0];
    const int*  ei     = (const int*)d_in[1];
    const void* W1l    = d_in[2];
    const void* b1     = d_in[3];
    const void* W1r    = d_in[4];
    const void* W2l    = d_in[5];
    const void* b2     = d_in[6];
    const void* W2r    = d_in[7];

    uint8_t* ws = (uint8_t*)d_ws;
    size_t off = 0;
    auto alloc = [&](size_t b) -> void* {
        void* p = ws + off;
        off += (b + 255) & ~(size_t)255;
        return p;
    };
    int*      histM       = (int*)alloc((size_t)NB * NBLK * 4);
    int*      bucket_tot  = (int*)alloc((NB + 4) * 4);
    int*      deg         = (int*)alloc((size_t)NN * 4);
    float*    inv_deg     = (float*)alloc((size_t)NN * 4);
    int*      row_start   = (int*)alloc((size_t)NN * 4);
    int*      csr         = (int*)alloc((size_t)NE * 4);
    uint32_t* xb          = (uint32_t*)alloc((size_t)NN * 64 * 4);
    uint16_t* bias_buf    = (uint16_t*)alloc(384 * 2);
    uint16_t* h           = (uint16_t*)alloc((size_t)NN * 256 * 2);
    uint16_t* t           = (uint16_t*)alloc((size_t)NN * 128 * 2);
    float*    u           = (float*)alloc((size_t)NN * 128 * 4);
    uint16_t* w1l_sw      = (uint16_t*)alloc(128 * 256 * 2);
    uint16_t* w1r_sw      = (uint16_t*)alloc(128 * 256 * 2);
    uint16_t* w2l_sw      = (uint16_t*)alloc(256 * 128 * 2);
    uint16_t* w2r_sw      = (uint16_t*)alloc(256 * 128 * 2);

    // staging aliases h (3.2 MB <= 25.6 MB; fully consumed by build_csr before h is written)
    uint32_t* staging = (uint32_t*)h;

    hist_pass<<<NBLK, 256, 0, stream>>>(ei, histM);
    scan_rows<<<NB, 512, 0, stream>>>(histM, bucket_tot);
    scatter_pass<<<NBLK, 256, 0, stream>>>(ei, histM, bucket_tot, staging);
    build_csr<<<NB, 256, 0, stream>>>(staging, bucket_tot, row_start, deg, inv_deg, csr);

    norm_all<<<NORMX_BLKS + 66, 256, 0, stream>>>(x_raw, W1l, b1, W1r, W2l, b2, W2r,
                                                  xb, w1l_sw, w1r_sw, w2l_sw, w2r_sw, bias_buf);

    // layer 1 fused: h = relu(mean_gather(x)@W1l + x@W1r + b1)
    fused_l1<<<(NN + 63) / 64, 256, 0, stream>>>(xb, row_start, deg, csr, inv_deg,
                                                 (const uint16_t*)xb, w1l_sw, w1r_sw, bias_buf, h);
    // layer 2: t = h@W2l, u = h@W2r + b2 ; out = A·t + u
    gemm2_v3<<<1564, 256, 0, stream>>>(h, w2l_sw, w2r_sw, bias_buf + 256, t, u);
    agg_final_v2<<<NN / 8, 256, 0, stream>>>((const uint32_t*)t, row_start, deg, csr, inv_deg,
                                             (const f32x4*)u, (f32x4*)d_out);
}

// Round 6
// 255.635 us; speedup vs baseline: 1.1855x; 1.1855x over previous
//
#include <hip/hip_runtime.h>
#include <hip/hip_bf16.h>
#include <stdint.h>

#define NN 50000
#define NE 800000
#define NB 196            // dst buckets: dst>>8 (256 nodes each)
#define EPB 2048
#define NBLK ((NE + EPB - 1) / EPB)   // 391
#define BCAP 8192         // per-bucket staging capacity (max bucket ~4350)

typedef __attribute__((ext_vector_type(8))) __bf16 bf16x8;
typedef __attribute__((ext_vector_type(4))) float f32x4;
typedef __attribute__((ext_vector_type(4))) int i32x4;

__device__ __forceinline__ float bflo(uint32_t u) { return __uint_as_float(u << 16); }
__device__ __forceinline__ float bfhi(uint32_t u) { return __uint_as_float(u & 0xffff0000u); }
__device__ __forceinline__ uint16_t f2bf(float f) {
    uint32_t u = __float_as_uint(f);
    u += 0x7fffu + ((u >> 16) & 1u);   // RNE
    return (uint16_t)(u >> 16);
}
__device__ __forceinline__ float bf2f(uint16_t h) { return __uint_as_float(((uint32_t)h) << 16); }

// bijective XCD-chunked block swizzle (m204 variant)
__device__ __forceinline__ int xcd_swz(int bid, int nwg) {
    int q = nwg >> 3, r = nwg & 7;
    int xcd = bid & 7, idx = bid >> 3;
    int base = (xcd < r) ? xcd * (q + 1) : r * (q + 1) + (xcd - r) * q;
    return base + idx;
}

// per-block edge-layout detection (int64 vs int32)
__device__ __forceinline__ int detect_i64(const int* ei, int* sh_cnt) {
    int t = threadIdx.x;
    if (t == 0) *sh_cnt = 0;
    __syncthreads();
    if (t < 64) atomicAdd(sh_cnt, (ei[2 * t + 1] != 0) ? 1 : 0);
    __syncthreads();
    return (*sh_cnt < 4) ? 1 : 0;
}

// per-block x-dtype detection (fp32 vs bf16)
__device__ __forceinline__ int detect_fp32(const uint32_t* xu, int* sh_cnt) {
    int t = threadIdx.x;
    if (t == 0) *sh_cnt = 0;
    __syncthreads();
    uint32_t u = xu[t & 255];
    uint32_t lo = u & 0xffffu;
    uint32_t e = (lo >> 7) & 0xffu;
    int ok = (lo == 0u) || (e >= 96u && e <= 150u);
    if (t < 256) atomicAdd(sh_cnt, ok);
    __syncthreads();
    return (*sh_cnt < 192) ? 1 : 0;
}

// ---------------- prep kernel 1: count + reserve + scatter (single kernel) ----------------
// Per block: LDS bucket histogram over its 2048 edges, one global atomicAdd per
// non-empty bucket to reserve a run in that bucket's fixed-stride region, then
// scatter. staging entry: (dst&0xff)<<16 | src   (NN < 2^16)
__global__ __launch_bounds__(256) void scatter1(const int* __restrict__ ei,
                                                int* __restrict__ bucket_cur,
                                                uint32_t* __restrict__ staging) {
    __shared__ int hist[NB];
    __shared__ int curs[NB];
    __shared__ int shc;
    int fl = detect_i64(ei, &shc);
    int t = threadIdx.x;
    for (int i = t; i < NB; i += 256) hist[i] = 0;
    __syncthreads();
    int base = blockIdx.x * EPB;
    for (int i = 0; i < EPB; i += 256) {   // pass 1: count (ei read #1)
        int e = base + i + t;
        if (e < NE) {
            int d = fl ? ei[2 * NE + 2 * e] : ei[NE + e];
            atomicAdd(&hist[d >> 8], 1);
        }
    }
    __syncthreads();
    for (int i = t; i < NB; i += 256)      // reserve runs
        curs[i] = (hist[i] > 0) ? atomicAdd(&bucket_cur[i], hist[i]) : 0;
    __syncthreads();
    for (int i = 0; i < EPB; i += 256) {   // pass 2: scatter (ei re-read from L2)
        int e = base + i + t;
        if (e < NE) {
            int s, d;
            if (fl) { s = ei[2 * e]; d = ei[2 * NE + 2 * e]; }
            else    { s = ei[e];     d = ei[NE + e]; }
            int b = d >> 8;
            int p = atomicAdd(&curs[b], 1);
            staging[b * BCAP + p] = ((uint32_t)(d & 0xff) << 16) | (uint32_t)s;
        }
    }
}

// ---------------- prep kernel 2 (role-split): CSR build (blocks 0..195) +
//                  x-norm (blocks 196..6445) + weight swizzle (blocks 6446..6511) ----------------
#define NORMX_BLKS 6250   // NN*32/256
__global__ __launch_bounds__(256) void csr_norm(const uint32_t* __restrict__ staging,
                                                const int* __restrict__ bucket_cur,
                                                const void* __restrict__ x,
                                                const void* __restrict__ w1l, const void* __restrict__ b1,
                                                const void* __restrict__ w1r, const void* __restrict__ w2l,
                                                const void* __restrict__ b2, const void* __restrict__ w2r,
                                                int* __restrict__ row_start, int* __restrict__ deg,
                                                float* __restrict__ inv_deg, int* __restrict__ csr,
                                                uint32_t* __restrict__ xb,
                                                uint16_t* __restrict__ w1l_sw, uint16_t* __restrict__ w1r_sw,
                                                uint16_t* __restrict__ w2l_sw, uint16_t* __restrict__ w2r_sw,
                                                uint16_t* __restrict__ bias_buf) {
    int blk = blockIdx.x;
    int t = threadIdx.x;
    if (blk < NB) {
        // ---- CSR role ----
        __shared__ int degs[256];
        __shared__ int sm[256];
        __shared__ int curs[256];
        int beg = blk * BCAP, cnt = bucket_cur[blk];
        degs[t] = 0;
        __syncthreads();
        for (int i = t; i < cnt; i += 256) atomicAdd(&degs[(staging[beg + i] >> 16) & 0xff], 1);
        __syncthreads();
        int d = degs[t];
        sm[t] = d;
        __syncthreads();
        for (int o = 1; o < 256; o <<= 1) {
            int x2 = (t >= o) ? sm[t - o] : 0;
            __syncthreads();
            sm[t] += x2;
            __syncthreads();
        }
        int excl = sm[t] - d;
        curs[t] = excl;
        int node = blk * 256 + t;
        if (node < NN) {
            row_start[node] = beg + excl;
            deg[node] = d;
            inv_deg[node] = 1.0f / (float)(d > 0 ? d : 1);
        }
        __syncthreads();
        for (int i = t; i < cnt; i += 256) {
            uint32_t u = staging[beg + i];
            int dl = (u >> 16) & 0xff;
            int p = atomicAdd(&curs[dl], 1);
            csr[beg + p] = (int)(u & 0xffffu);
        }
        return;
    }
    // ---- norm roles ----
    __shared__ int shc;
    int fp32 = detect_fp32((const uint32_t*)x, &shc);
    int nb = blk - NB;
    if (nb < NORMX_BLKS) {
        int i = nb * 256 + t;  // < NN*32
        if (fp32) {
            f32x4 v = ((const f32x4*)x)[i];
            uint2 o;
            o.x = (uint32_t)f2bf(v[0]) | ((uint32_t)f2bf(v[1]) << 16);
            o.y = (uint32_t)f2bf(v[2]) | ((uint32_t)f2bf(v[3]) << 16);
            ((uint2*)xb)[i] = o;
        } else {
            ((uint2*)xb)[i] = ((const uint2*)x)[i];
        }
        return;
    }
    int tid = (nb - NORMX_BLKS) * 256 + t;
    if (tid < 16384) {
        int frag = tid >> 6, lane = tid & 63;
        const void* srcw; uint16_t* dst; int N; int fl;
        if (frag < 64)       { srcw = w1l; dst = w1l_sw; N = 256; fl = frag; }
        else if (frag < 128) { srcw = w1r; dst = w1r_sw; N = 256; fl = frag - 64; }
        else if (frag < 192) { srcw = w2l; dst = w2l_sw; N = 128; fl = frag - 128; }
        else                 { srcw = w2r; dst = w2r_sw; N = 128; fl = frag - 192; }
        int NTm = N >> 4;
        int kt = fl / NTm, nt = fl - kt * NTm;
        int k0 = kt * 32 + (lane >> 4) * 8, n = nt * 16 + (lane & 15);
        uint16_t* d = dst + (size_t)fl * 512 + lane * 8;
#pragma unroll
        for (int j = 0; j < 8; j++) {
            int si = (k0 + j) * N + n;
            d[j] = fp32 ? f2bf(((const float*)srcw)[si]) : ((const uint16_t*)srcw)[si];
        }
    } else if (tid < 16384 + 384) {
        int j = tid - 16384;
        const void* s = (j < 256) ? b1 : b2;
        int jj = (j < 256) ? j : j - 256;
        bias_buf[j] = fp32 ? f2bf(((const float*)s)[jj]) : ((const uint16_t*)s)[jj];
    }
}

// ---------------- mean aggregation v2: 2 nodes/wave, dwordx2 gathers ----------------
__global__ __launch_bounds__(256) void agg_mean_v2(const uint32_t* __restrict__ xu,
                                                   const int* __restrict__ row_start,
                                                   const int* __restrict__ deg,
                                                   const int* __restrict__ csr,
                                                   const float* __restrict__ inv_deg,
                                                   uint32_t* __restrict__ outu) {
    int wave = threadIdx.x >> 6, lane = threadIdx.x & 63;
    int half = lane >> 5, l = lane & 31;
    int node = blockIdx.x * 8 + wave * 2 + half;
    int beg = row_start[node], end = beg + deg[node];
    float lx[8], hx[8], ly[8], hy[8];
#pragma unroll
    for (int k = 0; k < 8; k++) { lx[k] = 0.f; hx[k] = 0.f; ly[k] = 0.f; hy[k] = 0.f; }
    int j = beg;
    for (; j + 8 <= end; j += 8) {
        int idx[8];
#pragma unroll
        for (int k = 0; k < 8; k++) idx[k] = csr[j + k];
#pragma unroll
        for (int k = 0; k < 8; k++) {
            uint2 v = *(const uint2*)(xu + (size_t)idx[k] * 64 + l * 2);
            lx[k] += bflo(v.x); hx[k] += bfhi(v.x);
            ly[k] += bflo(v.y); hy[k] += bfhi(v.y);
        }
    }
    for (; j < end; j++) {
        uint2 v = *(const uint2*)(xu + (size_t)csr[j] * 64 + l * 2);
        lx[0] += bflo(v.x); hx[0] += bfhi(v.x);
        ly[0] += bflo(v.y); hy[0] += bfhi(v.y);
    }
    float sc = inv_deg[node];
    float r0 = (((lx[0] + lx[1]) + (lx[2] + lx[3])) + ((lx[4] + lx[5]) + (lx[6] + lx[7]))) * sc;
    float r1 = (((hx[0] + hx[1]) + (hx[2] + hx[3])) + ((hx[4] + hx[5]) + (hx[6] + hx[7]))) * sc;
    float r2 = (((ly[0] + ly[1]) + (ly[2] + ly[3])) + ((ly[4] + ly[5]) + (ly[6] + ly[7]))) * sc;
    float r3 = (((hy[0] + hy[1]) + (hy[2] + hy[3])) + ((hy[4] + hy[5]) + (hy[6] + hy[7]))) * sc;
    uint2 o;
    o.x = (uint32_t)f2bf(r0) | ((uint32_t)f2bf(r1) << 16);
    o.y = (uint32_t)f2bf(r2) | ((uint32_t)f2bf(r3) << 16);
    *(uint2*)(outu + (size_t)node * 64 + l * 2) = o;
}

// final v2: out = mean_gather(t) + u, fp32 out; 2 nodes/wave, dwordx2 gathers, float4 stores
__global__ __launch_bounds__(256) void agg_final_v2(const uint32_t* __restrict__ tu,
                                                    const int* __restrict__ row_start,
                                                    const int* __restrict__ deg,
                                                    const int* __restrict__ csr,
                                                    const float* __restrict__ inv_deg,
                                                    const f32x4* __restrict__ u,
                                                    f32x4* __restrict__ out) {
    int wave = threadIdx.x >> 6, lane = threadIdx.x & 63;
    int half = lane >> 5, l = lane & 31;
    int node = blockIdx.x * 8 + wave * 2 + half;
    int beg = row_start[node], end = beg + deg[node];
    float lx[8], hx[8], ly[8], hy[8];
#pragma unroll
    for (int k = 0; k < 8; k++) { lx[k] = 0.f; hx[k] = 0.f; ly[k] = 0.f; hy[k] = 0.f; }
    int j = beg;
    for (; j + 8 <= end; j += 8) {
        int idx[8];
#pragma unroll
        for (int k = 0; k < 8; k++) idx[k] = csr[j + k];
#pragma unroll
        for (int k = 0; k < 8; k++) {
            uint2 v = *(const uint2*)(tu + (size_t)idx[k] * 64 + l * 2);
            lx[k] += bflo(v.x); hx[k] += bfhi(v.x);
            ly[k] += bflo(v.y); hy[k] += bfhi(v.y);
        }
    }
    for (; j < end; j++) {
        uint2 v = *(const uint2*)(tu + (size_t)csr[j] * 64 + l * 2);
        lx[0] += bflo(v.x); hx[0] += bfhi(v.x);
        ly[0] += bflo(v.y); hy[0] += bfhi(v.y);
    }
    float sc = inv_deg[node];
    f32x4 uv = u[(size_t)node * 32 + l];
    f32x4 r;
    r[0] = (((lx[0] + lx[1]) + (lx[2] + lx[3])) + ((lx[4] + lx[5]) + (lx[6] + lx[7]))) * sc + uv[0];
    r[1] = (((hx[0] + hx[1]) + (hx[2] + hx[3])) + ((hx[4] + hx[5]) + (hx[6] + hx[7]))) * sc + uv[1];
    r[2] = (((ly[0] + ly[1]) + (ly[2] + ly[3])) + ((ly[4] + ly[5]) + (ly[6] + ly[7]))) * sc + uv[2];
    r[3] = (((hy[0] + hy[1]) + (hy[2] + hy[3])) + ((hy[4] + hy[5]) + (hy[6] + hy[7]))) * sc + uv[3];
    out[(size_t)node * 32 + l] = r;
}

// ---------------- layer-1 GEMM v3: h = relu(A1@W1 + A2@W2 + bias), single fused loop ----------------
__global__ __launch_bounds__(256) void gemm1_v3(const uint16_t* __restrict__ A1,
                                                const uint16_t* __restrict__ A2,
                                                const uint16_t* __restrict__ W1sw,
                                                const uint16_t* __restrict__ W2sw,
                                                const uint16_t* __restrict__ bias,
                                                uint16_t* __restrict__ C) {
    __shared__ __align__(16) uint16_t cs[64][72];   // +8 pad, 144B row stride
    int wg = xcd_swz(blockIdx.x, 3128);
    int rg = wg >> 2, cg = wg & 3;
    int wave = threadIdx.x >> 6, lane = threadIdx.x & 63;
    int wr = wave >> 1, wc = wave & 1;
    int m = lane & 15, q = lane >> 4;
    int rowbase = rg * 64 + wr * 32;
    int gnt0 = cg * 4 + wc * 2;      // global 16-col frag base, NTF=16

    int ar[2];
#pragma unroll
    for (int rf = 0; rf < 2; rf++) {
        int r = rowbase + rf * 16 + m;
        ar[rf] = (r < NN) ? r : (NN - 1);
    }

    bf16x8 B1[4][2], B2[4][2];   // 64 VGPR preload (L2-resident weights)
#pragma unroll
    for (int kt = 0; kt < 4; kt++)
#pragma unroll
        for (int nt = 0; nt < 2; nt++) {
            B1[kt][nt] = *(const bf16x8*)(W1sw + ((size_t)(kt * 16 + gnt0 + nt)) * 512 + lane * 8);
            B2[kt][nt] = *(const bf16x8*)(W2sw + ((size_t)(kt * 16 + gnt0 + nt)) * 512 + lane * 8);
        }

    f32x4 acc[2][2];
#pragma unroll
    for (int rf = 0; rf < 2; rf++)
#pragma unroll
        for (int nt = 0; nt < 2; nt++)
#pragma unroll
            for (int i = 0; i < 4; i++) acc[rf][nt][i] = 0.f;

#pragma unroll
    for (int kt = 0; kt < 4; kt++) {
        bf16x8 a10 = *(const bf16x8*)(A1 + (size_t)ar[0] * 128 + kt * 32 + q * 8);
        bf16x8 a11 = *(const bf16x8*)(A1 + (size_t)ar[1] * 128 + kt * 32 + q * 8);
        bf16x8 a20 = *(const bf16x8*)(A2 + (size_t)ar[0] * 128 + kt * 32 + q * 8);
        bf16x8 a21 = *(const bf16x8*)(A2 + (size_t)ar[1] * 128 + kt * 32 + q * 8);
#pragma unroll
        for (int nt = 0; nt < 2; nt++) {
            acc[0][nt] = __builtin_amdgcn_mfma_f32_16x16x32_bf16(a10, B1[kt][nt], acc[0][nt], 0, 0, 0);
            acc[1][nt] = __builtin_amdgcn_mfma_f32_16x16x32_bf16(a11, B1[kt][nt], acc[1][nt], 0, 0, 0);
            acc[0][nt] = __builtin_amdgcn_mfma_f32_16x16x32_bf16(a20, B2[kt][nt], acc[0][nt], 0, 0, 0);
            acc[1][nt] = __builtin_amdgcn_mfma_f32_16x16x32_bf16(a21, B2[kt][nt], acc[1][nt], 0, 0, 0);
        }
    }

    // ---- epilogue: bias + relu -> LDS -> coalesced store ----
#pragma unroll
    for (int rf = 0; rf < 2; rf++)
#pragma unroll
        for (int nt = 0; nt < 2; nt++) {
            int coll = wc * 32 + nt * 16 + m;
            float bv = bf2f(bias[cg * 64 + coll]);
#pragma unroll
            for (int i = 0; i < 4; i++) {
                float v = fmaxf(acc[rf][nt][i] + bv, 0.f);
                cs[wr * 32 + rf * 16 + q * 4 + i][coll] = f2bf(v);
            }
        }
    __syncthreads();
    int tt = threadIdx.x;
#pragma unroll
    for (int rr = 0; rr < 2; rr++) {
        int row = rr * 32 + (tt >> 3);
        int grow = rg * 64 + row;
        if (grow < NN)
            *(i32x4*)(C + (size_t)grow * 256 + cg * 64 + (tt & 7) * 8) =
                *(const i32x4*)&cs[row][(tt & 7) * 8];
    }
}

// ---------------- layer-2 GEMM v3: t = A@W1 (bf16), u = A@W2 + bias (fp32) ----------------
__global__ __launch_bounds__(256) void gemm2_v3(const uint16_t* __restrict__ A,
                                                const uint16_t* __restrict__ W1sw,
                                                const uint16_t* __restrict__ W2sw,
                                                const uint16_t* __restrict__ bias,
                                                uint16_t* __restrict__ T,
                                                float* __restrict__ U) {
    __shared__ __align__(16) uint16_t ts[64][72];   // 9216 B
    __shared__ __align__(16) float us[64][68];      // 17408 B
    int wg = xcd_swz(blockIdx.x, 1564);
    int rg = wg >> 1, cg = wg & 1;
    int wave = threadIdx.x >> 6, lane = threadIdx.x & 63;
    int wr = wave >> 1, wc = wave & 1;
    int m = lane & 15, q = lane >> 4;
    int rowbase = rg * 64 + wr * 32;
    int gnt0 = cg * 4 + wc * 2;      // global 16-col frag base, NTF=8

    int ar[2];
#pragma unroll
    for (int rf = 0; rf < 2; rf++) {
        int r = rowbase + rf * 16 + m;
        ar[rf] = (r < NN) ? r : (NN - 1);
    }

    f32x4 acc1[2][2], acc2[2][2];
#pragma unroll
    for (int rf = 0; rf < 2; rf++)
#pragma unroll
        for (int nt = 0; nt < 2; nt++)
#pragma unroll
            for (int i = 0; i < 4; i++) { acc1[rf][nt][i] = 0.f; acc2[rf][nt][i] = 0.f; }

#pragma unroll
    for (int kt = 0; kt < 8; kt++) {
        bf16x8 b10 = *(const bf16x8*)(W1sw + ((size_t)(kt * 8 + gnt0 + 0)) * 512 + lane * 8);
        bf16x8 b11 = *(const bf16x8*)(W1sw + ((size_t)(kt * 8 + gnt0 + 1)) * 512 + lane * 8);
        bf16x8 b20 = *(const bf16x8*)(W2sw + ((size_t)(kt * 8 + gnt0 + 0)) * 512 + lane * 8);
        bf16x8 b21 = *(const bf16x8*)(W2sw + ((size_t)(kt * 8 + gnt0 + 1)) * 512 + lane * 8);
        bf16x8 a0 = *(const bf16x8*)(A + (size_t)ar[0] * 256 + kt * 32 + q * 8);
        bf16x8 a1 = *(const bf16x8*)(A + (size_t)ar[1] * 256 + kt * 32 + q * 8);
        acc1[0][0] = __builtin_amdgcn_mfma_f32_16x16x32_bf16(a0, b10, acc1[0][0], 0, 0, 0);
        acc1[0][1] = __builtin_amdgcn_mfma_f32_16x16x32_bf16(a0, b11, acc1[0][1], 0, 0, 0);
        acc1[1][0] = __builtin_amdgcn_mfma_f32_16x16x32_bf16(a1, b10, acc1[1][0], 0, 0, 0);
        acc1[1][1] = __builtin_amdgcn_mfma_f32_16x16x32_bf16(a1, b11, acc1[1][1], 0, 0, 0);
        acc2[0][0] = __builtin_amdgcn_mfma_f32_16x16x32_bf16(a0, b20, acc2[0][0], 0, 0, 0);
        acc2[0][1] = __builtin_amdgcn_mfma_f32_16x16x32_bf16(a0, b21, acc2[0][1], 0, 0, 0);
        acc2[1][0] = __builtin_amdgcn_mfma_f32_16x16x32_bf16(a1, b20, acc2[1][0], 0, 0, 0);
        acc2[1][1] = __builtin_amdgcn_mfma_f32_16x16x32_bf16(a1, b21, acc2[1][1], 0, 0, 0);
    }

#pragma unroll
    for (int rf = 0; rf < 2; rf++)
#pragma unroll
        for (int nt = 0; nt < 2; nt++) {
            int coll = wc * 32 + nt * 16 + m;
            float bv = bf2f(bias[cg * 64 + coll]);
#pragma unroll
            for (int i = 0; i < 4; i++) {
                int rl = wr * 32 + rf * 16 + q * 4 + i;
                ts[rl][coll] = f2bf(acc1[rf][nt][i]);
                us[rl][coll] = acc2[rf][nt][i] + bv;
            }
        }
    __syncthreads();
    int tt = threadIdx.x;
#pragma unroll
    for (int rr = 0; rr < 2; rr++) {
        int row = rr * 32 + (tt >> 3);
        int grow = rg * 64 + row;
        if (grow < NN)
            *(i32x4*)(T + (size_t)grow * 128 + cg * 64 + (tt & 7) * 8) =
                *(const i32x4*)&ts[row][(tt & 7) * 8];
    }
#pragma unroll
    for (int rr = 0; rr < 4; rr++) {
        int row = rr * 16 + (tt >> 4);
        int grow = rg * 64 + row;
        if (grow < NN)
            *(f32x4*)(U + (size_t)grow * 128 + cg * 64 + (tt & 15) * 4) =
                *(const f32x4*)&us[row][(tt & 15) * 4];
    }
}

extern "C" void kernel_launch(void* const* d_in, const int* in_sizes, int n_in,
                              void* d_out, int out_size, void* d_ws, size_t ws_size,
                              hipStream_t stream) {
    const void* x_raw  = d_in[0];
    const int*  ei     = (const int*)d_in[1];
    const void* W1l    = d_in[2];
    const void* b1     = d_in[3];
    const void* W1r    = d_in[4];
    const void* W2l    = d_in[5];
    const void* b2     = d_in[6];
    const void* W2r    = d_in[7];

    uint8_t* ws = (uint8_t*)d_ws;
    size_t off = 0;
    auto alloc = [&](size_t b) -> void* {
        void* p = ws + off;
        off += (b + 255) & ~(size_t)255;
        return p;
    };
    int*      bucket_cur  = (int*)alloc((NB + 4) * 4);
    int*      deg         = (int*)alloc((size_t)NN * 4);
    float*    inv_deg     = (float*)alloc((size_t)NN * 4);
    int*      row_start   = (int*)alloc((size_t)NN * 4);
    int*      csr         = (int*)alloc((size_t)NB * BCAP * 4);   // 6.4 MB, bucket-strided
    uint32_t* xb          = (uint32_t*)alloc((size_t)NN * 64 * 4);
    uint16_t* bias_buf    = (uint16_t*)alloc(384 * 2);
    uint16_t* agg         = (uint16_t*)alloc((size_t)NN * 128 * 2);
    uint16_t* h           = (uint16_t*)alloc((size_t)NN * 256 * 2);
    uint16_t* t           = (uint16_t*)alloc((size_t)NN * 128 * 2);
    float*    u           = (float*)alloc((size_t)NN * 128 * 4);
    uint16_t* w1l_sw      = (uint16_t*)alloc(128 * 256 * 2);
    uint16_t* w1r_sw      = (uint16_t*)alloc(128 * 256 * 2);
    uint16_t* w2l_sw      = (uint16_t*)alloc(256 * 128 * 2);
    uint16_t* w2r_sw      = (uint16_t*)alloc(256 * 128 * 2);

    // staging aliases h (6.4 MB <= 25.6 MB; fully consumed by csr_norm before h is written)
    uint32_t* staging = (uint32_t*)h;

    hipMemsetAsync(bucket_cur, 0, NB * 4, stream);
    scatter1<<<NBLK, 256, 0, stream>>>(ei, bucket_cur, staging);
    csr_norm<<<NB + NORMX_BLKS + 66, 256, 0, stream>>>(staging, bucket_cur, x_raw,
                                                       W1l, b1, W1r, W2l, b2, W2r,
                                                       row_start, deg, inv_deg, csr,
                                                       xb, w1l_sw, w1r_sw, w2l_sw, w2r_sw, bias_buf);

    // layer 1: agg = A·x ; h = relu(agg@W1l + x@W1r + b1)
    agg_mean_v2<<<NN / 8, 256, 0, stream>>>(xb, row_start, deg, csr, inv_deg, (uint32_t*)agg);
    gemm1_v3<<<3128, 256, 0, stream>>>(agg, (const uint16_t*)xb, w1l_sw, w1r_sw, bias_buf, h);
    // layer 2: t = h@W2l, u = h@W2r + b2 ; out = A·t + u
    gemm2_v3<<<1564, 256, 0, stream>>>(h, w2l_sw, w2r_sw, bias_buf + 256, t, u);
    agg_final_v2<<<NN / 8, 256, 0, stream>>>((const uint32_t*)t, row_start, deg, csr, inv_deg,
                                             (const f32x4*)u, (f32x4*)d_out);
}